// Round 1
// baseline (349.005 us; speedup 1.0000x reference)
//
#include <hip/hip_runtime.h>

typedef short bf16x8 __attribute__((ext_vector_type(8)));
typedef float f32x4 __attribute__((ext_vector_type(4)));
typedef unsigned short u16;
typedef unsigned short u16x8 __attribute__((ext_vector_type(8)));

#define MFMA16(a, b, c) __builtin_amdgcn_mfma_f32_16x16x32_bf16((a), (b), (c), 0, 0, 0)

__device__ __forceinline__ u16 f2bf(float f) {
  unsigned u = __builtin_bit_cast(unsigned, f);
  return (u16)((u + 0x7fffu + ((u >> 16) & 1u)) >> 16);
}

__device__ __forceinline__ void gload_lds16(const u16* g, u16* lds) {
  __builtin_amdgcn_global_load_lds((__attribute__((address_space(1))) void*)g,
                                   (__attribute__((address_space(3))) void*)lds,
                                   16, 0, 0);
}

// ---------------- fp32 -> bf16 conversion (x + 4 weight mats) ----------------
__global__ __launch_bounds__(256) void cvt_all(
    const float* __restrict__ x, const float* __restrict__ w0,
    const float* __restrict__ w1, const float* __restrict__ w2,
    const float* __restrict__ w3, u16* __restrict__ xb, u16* __restrict__ wb) {
  long i = (long)(blockIdx.x * 256 + threadIdx.x) * 8;
  const float* src; u16* dst; long off;
  if (i < 4194304) { src = x; dst = xb; off = i; }
  else {
    long k = i - 4194304; int w = (int)(k >> 20); off = k & 1048575;
    src = (w == 0) ? w0 : (w == 1) ? w1 : (w == 2) ? w2 : w3;
    dst = wb + (long)w * 1048576;
  }
  float4 a = *(const float4*)(src + off);
  float4 b = *(const float4*)(src + off + 4);
  u16x8 o;
  o[0] = f2bf(a.x); o[1] = f2bf(a.y); o[2] = f2bf(a.z); o[3] = f2bf(a.w);
  o[4] = f2bf(b.x); o[5] = f2bf(b.y); o[6] = f2bf(b.z); o[7] = f2bf(b.w);
  *(u16x8*)(dst + off) = o;
}

// ---------------- GEMM  C[M,N] = A[M,K] * B[N,K]^T  (bf16 in, fp32 acc) -----
// MODE 0: QKV fused (blockIdx.y: mat = y>>3, nb = y&7), bf16 out, Q scaled.
// MODE 1: out-proj, fp32 out + bias.
template <int MODE>
__global__ __launch_bounds__(256) void gemm_bt(
    const u16* __restrict__ A, const u16* __restrict__ Bw,
    u16* __restrict__ Co, float* __restrict__ Cf, const float* __restrict__ bias) {
  constexpr int K = 1024;
  __shared__ u16 As[128 * 32];
  __shared__ u16 Bs[128 * 32];
  const int tid = threadIdx.x, w = tid >> 6, l = tid & 63;
  const int lg = l >> 4, lr = l & 15;
  const int mb = blockIdx.x;
  int mat, nb;
  if (MODE == 0) { mat = blockIdx.y >> 3; nb = blockIdx.y & 7; }
  else           { mat = 0;               nb = blockIdx.y;     }
  const u16* __restrict__ Bp = Bw + (long)mat * 1048576;
  const int wr = w >> 1, wc = w & 1;
  f32x4 acc[4][4] = {};
  const int srow = (l >> 2), scol = (l & 3) * 8;
  for (int kt = 0; kt < K / 32; ++kt) {
    const int kb = kt * 32;
    __syncthreads();  // previous tile's frag reads complete
#pragma unroll
    for (int i = 0; i < 2; ++i) {
      int r = w * 32 + i * 16 + srow;
      gload_lds16(A  + (long)(mb * 128 + r) * K + kb + scol, &As[(w * 2 + i) * 512]);
      gload_lds16(Bp + (long)(nb * 128 + r) * K + kb + scol, &Bs[(w * 2 + i) * 512]);
    }
    __syncthreads();  // drains vmcnt -> LDS tiles valid
    bf16x8 af[4], bf[4];
#pragma unroll
    for (int m = 0; m < 4; ++m) af[m] = *(const bf16x8*)&As[(wr * 64 + m * 16 + lr) * 32 + lg * 8];
#pragma unroll
    for (int n = 0; n < 4; ++n) bf[n] = *(const bf16x8*)&Bs[(wc * 64 + n * 16 + lr) * 32 + lg * 8];
#pragma unroll
    for (int m = 0; m < 4; ++m)
#pragma unroll
      for (int n = 0; n < 4; ++n)
        acc[m][n] = MFMA16(af[m], bf[n], acc[m][n]);
  }
  const int row0 = mb * 128 + wr * 64, col0 = nb * 128 + wc * 64;
#pragma unroll
  for (int m = 0; m < 4; ++m)
#pragma unroll
    for (int n = 0; n < 4; ++n)
#pragma unroll
      for (int rr = 0; rr < 4; ++rr) {
        int row = row0 + m * 16 + lg * 4 + rr;
        int col = col0 + n * 16 + lr;
        float v = acc[m][n][rr];
        if (MODE == 0) {
          if (mat == 0) v *= 0.18033688011112042f;  // 0.125 * log2(e), folded softmax scale
          Co[(long)mat * 4194304 + (long)row * 1024 + col] = f2bf(v);
        } else {
          Cf[(long)row * 1024 + col] = v + bias[col];
        }
      }
}

// ---------------- flash attention, 16 heads, d=64, KVBLK=64 ----------------
__global__ __launch_bounds__(256) void attn(
    const u16* __restrict__ Qg, const u16* __restrict__ Kg,
    const u16* __restrict__ Vg, u16* __restrict__ Og) {
  __shared__ u16 Ks[64 * 72];        // K tile [k][d], row pad 72 (16B aligned, 8/bank min)
  __shared__ u16 Vs[64 * 72];        // V^T tile [d][k]
  __shared__ u16 Ps[4 * 32 * 72];    // per-wave P [32 q][64 k]
  const int tid = threadIdx.x, w = tid >> 6, l = tid & 63;
  const int lg = l >> 4, lr = l & 15;
  const int hb = blockIdx.y * 64;
  const int q0 = blockIdx.x * 128 + w * 32;
  bf16x8 qf[2][2];
#pragma unroll
  for (int m = 0; m < 2; ++m)
#pragma unroll
    for (int dc = 0; dc < 2; ++dc)
      qf[m][dc] = *(const bf16x8*)&Qg[(long)(q0 + m * 16 + lr) * 1024 + hb + dc * 32 + lg * 8];
  f32x4 o[2][4] = {};
  float mr[2][4], ls[2][4];
#pragma unroll
  for (int m = 0; m < 2; ++m)
#pragma unroll
    for (int rr = 0; rr < 4; ++rr) { mr[m][rr] = -1e30f; ls[m][rr] = 0.f; }
  u16* Pw = &Ps[w * 32 * 72];
  const int kr = tid >> 3, kc8 = tid & 7;
  for (int kt = 0; kt < 64; ++kt) {
    const long kb = (long)kt * 64;
    __syncthreads();  // all waves done reading previous K/V tiles
#pragma unroll
    for (int i = 0; i < 2; ++i) {
      int row = kr + 32 * i;
      *(bf16x8*)&Ks[row * 72 + kc8 * 8] =
          *(const bf16x8*)&Kg[(kb + row) * 1024 + hb + kc8 * 8];
    }
    {  // V staged transposed, two rows pair-packed per b32 write
      int r0 = (tid >> 3) * 2;
      bf16x8 v0 = *(const bf16x8*)&Vg[(kb + r0) * 1024 + hb + kc8 * 8];
      bf16x8 v1 = *(const bf16x8*)&Vg[(kb + r0 + 1) * 1024 + hb + kc8 * 8];
#pragma unroll
      for (int j = 0; j < 8; ++j) {
        unsigned pk = (unsigned)(u16)v0[j] | ((unsigned)(u16)v1[j] << 16);
        *(unsigned*)&Vs[(kc8 * 8 + j) * 72 + r0] = pk;
      }
    }
    __syncthreads();
    // S = Q*K^T (scale+log2e already folded into Q)
    f32x4 S[2][4] = {};
#pragma unroll
    for (int nt = 0; nt < 4; ++nt)
#pragma unroll
      for (int dc = 0; dc < 2; ++dc) {
        bf16x8 kf = *(const bf16x8*)&Ks[(nt * 16 + lr) * 72 + dc * 32 + lg * 8];
        S[0][nt] = MFMA16(qf[0][dc], kf, S[0][nt]);
        S[1][nt] = MFMA16(qf[1][dc], kf, S[1][nt]);
      }
    // online softmax (rows live on (lg, reg); reduce over 16 lanes = cols)
#pragma unroll
    for (int m = 0; m < 2; ++m) {
      float mx[4], al[4], sm[4];
#pragma unroll
      for (int rr = 0; rr < 4; ++rr)
        mx[rr] = fmaxf(fmaxf(S[m][0][rr], S[m][1][rr]), fmaxf(S[m][2][rr], S[m][3][rr]));
#pragma unroll
      for (int d = 1; d < 16; d <<= 1)
#pragma unroll
        for (int rr = 0; rr < 4; ++rr) mx[rr] = fmaxf(mx[rr], __shfl_xor(mx[rr], d));
#pragma unroll
      for (int rr = 0; rr < 4; ++rr) {
        float mn = fmaxf(mr[m][rr], mx[rr]);
        al[rr] = __builtin_amdgcn_exp2f(mr[m][rr] - mn);
        mr[m][rr] = mn;
#pragma unroll
        for (int nt = 0; nt < 4; ++nt)
          S[m][nt][rr] = __builtin_amdgcn_exp2f(S[m][nt][rr] - mn);
        sm[rr] = (S[m][0][rr] + S[m][1][rr]) + (S[m][2][rr] + S[m][3][rr]);
      }
#pragma unroll
      for (int d = 1; d < 16; d <<= 1)
#pragma unroll
        for (int rr = 0; rr < 4; ++rr) sm[rr] += __shfl_xor(sm[rr], d);
#pragma unroll
      for (int rr = 0; rr < 4; ++rr) ls[m][rr] = ls[m][rr] * al[rr] + sm[rr];
#pragma unroll
      for (int dt = 0; dt < 4; ++dt)
#pragma unroll
        for (int rr = 0; rr < 4; ++rr) o[m][dt][rr] *= al[rr];
#pragma unroll
      for (int nt = 0; nt < 4; ++nt)
#pragma unroll
        for (int rr = 0; rr < 4; ++rr)
          Pw[(m * 16 + lg * 4 + rr) * 72 + nt * 16 + lr] = f2bf(S[m][nt][rr]);
    }
    __syncthreads();  // P writes drained (lgkmcnt(0) before barrier)
    bf16x8 pf[2][2];
#pragma unroll
    for (int m = 0; m < 2; ++m)
#pragma unroll
      for (int kc = 0; kc < 2; ++kc)
        pf[m][kc] = *(const bf16x8*)&Pw[(m * 16 + lr) * 72 + kc * 32 + lg * 8];
#pragma unroll
    for (int dt = 0; dt < 4; ++dt)
#pragma unroll
      for (int kc = 0; kc < 2; ++kc) {
        bf16x8 vf = *(const bf16x8*)&Vs[(dt * 16 + lr) * 72 + kc * 32 + lg * 8];
        o[0][dt] = MFMA16(pf[0][kc], vf, o[0][dt]);
        o[1][dt] = MFMA16(pf[1][kc], vf, o[1][dt]);
      }
  }
#pragma unroll
  for (int m = 0; m < 2; ++m) {
    float inv[4];
#pragma unroll
    for (int rr = 0; rr < 4; ++rr) inv[rr] = 1.0f / ls[m][rr];
#pragma unroll
    for (int dt = 0; dt < 4; ++dt)
#pragma unroll
      for (int rr = 0; rr < 4; ++rr)
        Og[(long)(q0 + m * 16 + lg * 4 + rr) * 1024 + hb + dt * 16 + lr] =
            f2bf(o[m][dt][rr] * inv[rr]);
  }
}

extern "C" void kernel_launch(void* const* d_in, const int* in_sizes, int n_in,
                              void* d_out, int out_size, void* d_ws, size_t ws_size,
                              hipStream_t stream) {
  const float* x  = (const float*)d_in[0];
  const float* Wq = (const float*)d_in[1];
  const float* Wk = (const float*)d_in[2];
  const float* Wv = (const float*)d_in[3];
  const float* Wo = (const float*)d_in[4];
  const float* bo = (const float*)d_in[5];
  float* out = (float*)d_out;

  u16* xb  = (u16*)d_ws;            // 4096x1024 bf16
  u16* wb  = xb + 4194304;          // 4 x 1024x1024 bf16 (Wq,Wk,Wv,Wo)
  u16* qkv = wb + 4194304;          // Q,K,V each 4096x1024 bf16
  u16* ctx = qkv + 3 * 4194304;     // 4096x1024 bf16

  cvt_all<<<dim3(4096), dim3(256), 0, stream>>>(x, Wq, Wk, Wv, Wo, xb, wb);
  gemm_bt<0><<<dim3(32, 24), dim3(256), 0, stream>>>(xb, wb, qkv, nullptr, nullptr);
  attn<<<dim3(32, 16), dim3(256), 0, stream>>>(qkv, qkv + 4194304, qkv + 8388608, ctx);
  gemm_bt<1><<<dim3(32, 8), dim3(256), 0, stream>>>(ctx, wb + 3 * 1048576, nullptr, out, bo);
}

// Round 2
// 208.467 us; speedup vs baseline: 1.6741x; 1.6741x over previous
//
#include <hip/hip_runtime.h>

typedef short bf16x8 __attribute__((ext_vector_type(8)));
typedef float f32x4 __attribute__((ext_vector_type(4)));
typedef unsigned short u16;
typedef unsigned short u16x4 __attribute__((ext_vector_type(4)));
typedef unsigned short u16x8 __attribute__((ext_vector_type(8)));

#define MFMA16(a, b, c) __builtin_amdgcn_mfma_f32_16x16x32_bf16((a), (b), (c), 0, 0, 0)

__device__ __forceinline__ u16 f2bf(float f) {
  unsigned u = __builtin_bit_cast(unsigned, f);
  return (u16)((u + 0x7fffu + ((u >> 16) & 1u)) >> 16);
}

__device__ __forceinline__ void gload_lds16(const u16* g, u16* lds) {
  __builtin_amdgcn_global_load_lds((__attribute__((address_space(1))) void*)g,
                                   (__attribute__((address_space(3))) void*)lds,
                                   16, 0, 0);
}

// ---------------- fp32 -> bf16 conversion (x + 4 weight mats) ----------------
__global__ __launch_bounds__(256) void cvt_all(
    const float* __restrict__ x, const float* __restrict__ w0,
    const float* __restrict__ w1, const float* __restrict__ w2,
    const float* __restrict__ w3, u16* __restrict__ xb, u16* __restrict__ wb) {
  long i = (long)(blockIdx.x * 256 + threadIdx.x) * 8;
  const float* src; u16* dst; long off;
  if (i < 4194304) { src = x; dst = xb; off = i; }
  else {
    long k = i - 4194304; int w = (int)(k >> 20); off = k & 1048575;
    src = (w == 0) ? w0 : (w == 1) ? w1 : (w == 2) ? w2 : w3;
    dst = wb + (long)w * 1048576;
  }
  float4 a = *(const float4*)(src + off);
  float4 b = *(const float4*)(src + off + 4);
  u16x8 o;
  o[0] = f2bf(a.x); o[1] = f2bf(a.y); o[2] = f2bf(a.z); o[3] = f2bf(a.w);
  o[4] = f2bf(b.x); o[5] = f2bf(b.y); o[6] = f2bf(b.z); o[7] = f2bf(b.w);
  *(u16x8*)(dst + off) = o;
}

// ---------------- GEMM  C[M,N] = A[M,K] * B[N,K]^T  (bf16 in, fp32 acc) -----
template <int MODE>
__global__ __launch_bounds__(256) void gemm_bt(
    const u16* __restrict__ A, const u16* __restrict__ Bw,
    u16* __restrict__ Co, float* __restrict__ Cf, const float* __restrict__ bias) {
  constexpr int K = 1024;
  __shared__ u16 As[128 * 32];
  __shared__ u16 Bs[128 * 32];
  const int tid = threadIdx.x, w = tid >> 6, l = tid & 63;
  const int lg = l >> 4, lr = l & 15;
  const int mb = blockIdx.x;
  int mat, nb;
  if (MODE == 0) { mat = blockIdx.y >> 3; nb = blockIdx.y & 7; }
  else           { mat = 0;               nb = blockIdx.y;     }
  const u16* __restrict__ Bp = Bw + (long)mat * 1048576;
  const int wr = w >> 1, wc = w & 1;
  f32x4 acc[4][4] = {};
  const int srow = (l >> 2), scol = (l & 3) * 8;
  for (int kt = 0; kt < K / 32; ++kt) {
    const int kb = kt * 32;
    __syncthreads();
#pragma unroll
    for (int i = 0; i < 2; ++i) {
      int r = w * 32 + i * 16 + srow;
      gload_lds16(A  + (long)(mb * 128 + r) * K + kb + scol, &As[(w * 2 + i) * 512]);
      gload_lds16(Bp + (long)(nb * 128 + r) * K + kb + scol, &Bs[(w * 2 + i) * 512]);
    }
    __syncthreads();
    bf16x8 af[4], bf[4];
#pragma unroll
    for (int m = 0; m < 4; ++m) af[m] = *(const bf16x8*)&As[(wr * 64 + m * 16 + lr) * 32 + lg * 8];
#pragma unroll
    for (int n = 0; n < 4; ++n) bf[n] = *(const bf16x8*)&Bs[(wc * 64 + n * 16 + lr) * 32 + lg * 8];
#pragma unroll
    for (int m = 0; m < 4; ++m)
#pragma unroll
      for (int n = 0; n < 4; ++n)
        acc[m][n] = MFMA16(af[m], bf[n], acc[m][n]);
  }
  const int row0 = mb * 128 + wr * 64, col0 = nb * 128 + wc * 64;
#pragma unroll
  for (int m = 0; m < 4; ++m)
#pragma unroll
    for (int n = 0; n < 4; ++n)
#pragma unroll
      for (int rr = 0; rr < 4; ++rr) {
        int row = row0 + m * 16 + lg * 4 + rr;
        int col = col0 + n * 16 + lr;
        float v = acc[m][n][rr];
        if (MODE == 0) {
          if (mat == 0) v *= 0.18033688011112042f;  // 0.125 * log2(e): softmax in exp2 domain
          Co[(long)mat * 4194304 + (long)row * 1024 + col] = f2bf(v);
        } else {
          Cf[(long)row * 1024 + col] = v + bias[col];
        }
      }
}

// ---------------- flash attention, swapped-QK^T, 16 heads, d=64, KVBLK=64 ---
// S^T = mfma(K, Q): lane holds S[k = nt*16+lg*4+rr][q = m*16+lr] -> softmax is
// 15 in-lane ops + 2 shfl. ctx^T = mfma(V^T, P): o[m][dt][rr] has
// d = dt*16+lg*4+rr, q = m*16+lr. V^T tile XOR-swizzled (write+read same
// involution) -> conflict-free staging. P roundtrip via wave-private LDS,
// packed b64 writes (no barrier needed: same-wave DS is in-order).
__global__ __launch_bounds__(256) void attn(
    const u16* __restrict__ Qg, const u16* __restrict__ Kg,
    const u16* __restrict__ Vg, u16* __restrict__ Og) {
  __shared__ u16 Ks[64 * 72];      // [k][d], pitch 72
  __shared__ u16 Vs[64 * 72];      // [d][k], pitch 72, dword-col swizzled
  __shared__ u16 Ps[4 * 32 * 72];  // per-wave P [q 32][k 64], pitch 72
  const int tid = threadIdx.x, w = tid >> 6, l = tid & 63;
  const int lg = l >> 4, lr = l & 15;
  const int hb = blockIdx.y * 64;
  const int q0 = blockIdx.x * 128 + w * 32;

  // Q fragments (B-operand of QK^T): Q[q = m*16+lr][d = dc*32+lg*8]
  bf16x8 qf[2][2];
#pragma unroll
  for (int m = 0; m < 2; ++m)
#pragma unroll
    for (int dc = 0; dc < 2; ++dc)
      qf[m][dc] = *(const bf16x8*)&Qg[(long)(q0 + m * 16 + lr) * 1024 + hb + dc * 32 + lg * 8];

  f32x4 o[2][4] = {};
  float mr[2] = {-1e30f, -1e30f}, ls[2] = {0.f, 0.f};
  u16* Pw = &Ps[w * 32 * 72];

  // staging geometry: 256 threads cover K rows 0..63 (kr, kr+32) and V row
  // pairs (2*kr, 2*kr+1), column octet c8.
  const int kr = tid >> 3, c8 = tid & 7;
  const u16* Kgp = Kg + hb + c8 * 8;
  const u16* Vgp = Vg + hb + c8 * 8;
  bf16x8 kst0, kst1, vst0, vst1;

#define STAGE_LOAD(kt_)                                              \
  {                                                                  \
    long kb_ = (long)(kt_) * 64;                                     \
    kst0 = *(const bf16x8*)&Kgp[(kb_ + kr) * 1024];                  \
    kst1 = *(const bf16x8*)&Kgp[(kb_ + kr + 32) * 1024];             \
    vst0 = *(const bf16x8*)&Vgp[(kb_ + kr * 2) * 1024];              \
    vst1 = *(const bf16x8*)&Vgp[(kb_ + kr * 2 + 1) * 1024];          \
  }

#define STAGE_WRITE()                                                        \
  {                                                                          \
    *(bf16x8*)&Ks[kr * 72 + c8 * 8] = kst0;                                  \
    *(bf16x8*)&Ks[(kr + 32) * 72 + c8 * 8] = kst1;                           \
    const int cw = (kr ^ (c8 << 2)) * 2; /* swizzled dword col -> u16 */     \
    _Pragma("unroll")                                                        \
    for (int j = 0; j < 8; ++j) {                                            \
      unsigned pk = (unsigned)(u16)vst0[j] | ((unsigned)(u16)vst1[j] << 16); \
      *(unsigned*)&Vs[(c8 * 8 + j) * 72 + cw] = pk;                          \
    }                                                                        \
  }

  STAGE_LOAD(0);
  STAGE_WRITE();
  __syncthreads();

  for (int kt = 0; kt < 64; ++kt) {
    if (kt < 63) STAGE_LOAD(kt + 1);  // T14: issue next loads under compute

    // ---- S^T = K * Q^T (scale+log2e folded into Q upstream) ----
    f32x4 S[2][4] = {};
    __builtin_amdgcn_s_setprio(1);
#pragma unroll
    for (int nt = 0; nt < 4; ++nt)
#pragma unroll
      for (int dc = 0; dc < 2; ++dc) {
        bf16x8 kf = *(const bf16x8*)&Ks[(nt * 16 + lr) * 72 + dc * 32 + lg * 8];
        S[0][nt] = MFMA16(kf, qf[0][dc], S[0][nt]);
        S[1][nt] = MFMA16(kf, qf[1][dc], S[1][nt]);
      }
    __builtin_amdgcn_s_setprio(0);

    // ---- online softmax: lane owns q = m*16+lr, 16 k-values in-register ----
#pragma unroll
    for (int m = 0; m < 2; ++m) {
      float t0 = fmaxf(fmaxf(S[m][0][0], S[m][0][1]), fmaxf(S[m][0][2], S[m][0][3]));
      float t1 = fmaxf(fmaxf(S[m][1][0], S[m][1][1]), fmaxf(S[m][1][2], S[m][1][3]));
      float t2 = fmaxf(fmaxf(S[m][2][0], S[m][2][1]), fmaxf(S[m][2][2], S[m][2][3]));
      float t3 = fmaxf(fmaxf(S[m][3][0], S[m][3][1]), fmaxf(S[m][3][2], S[m][3][3]));
      float mx = fmaxf(fmaxf(t0, t1), fmaxf(t2, t3));
      mx = fmaxf(mx, __shfl_xor(mx, 16));
      mx = fmaxf(mx, __shfl_xor(mx, 32));
      float mn = fmaxf(mr[m], mx);
      float al = __builtin_amdgcn_exp2f(mr[m] - mn);
      mr[m] = mn;
      float sm = 0.f;
#pragma unroll
      for (int nt = 0; nt < 4; ++nt) {
#pragma unroll
        for (int rr = 0; rr < 4; ++rr) {
          S[m][nt][rr] = __builtin_amdgcn_exp2f(S[m][nt][rr] - mn);
          sm += S[m][nt][rr];
        }
      }
      sm += __shfl_xor(sm, 16);
      sm += __shfl_xor(sm, 32);
      ls[m] = ls[m] * al + sm;
#pragma unroll
      for (int dt = 0; dt < 4; ++dt)
#pragma unroll
        for (int rr = 0; rr < 4; ++rr) o[m][dt][rr] *= al;
      // P write: 4 consecutive k per lane -> packed b64, conflict-free
#pragma unroll
      for (int nt = 0; nt < 4; ++nt) {
        u16x4 pk;
        pk[0] = f2bf(S[m][nt][0]); pk[1] = f2bf(S[m][nt][1]);
        pk[2] = f2bf(S[m][nt][2]); pk[3] = f2bf(S[m][nt][3]);
        *(u16x4*)&Pw[(m * 16 + lr) * 72 + nt * 16 + lg * 4] = pk;
      }
    }

    // ---- ctx^T += V^T * P^T  (A = V^T frag, B = P natural [q][k] frag) ----
    bf16x8 pf[2][2];
#pragma unroll
    for (int m = 0; m < 2; ++m)
#pragma unroll
      for (int kc = 0; kc < 2; ++kc)
        pf[m][kc] = *(const bf16x8*)&Pw[(m * 16 + lr) * 72 + kc * 32 + lg * 8];
    __builtin_amdgcn_s_setprio(1);
#pragma unroll
    for (int dt = 0; dt < 4; ++dt) {
      const int row_d = dt * 16 + lr;
#pragma unroll
      for (int kc = 0; kc < 2; ++kc) {
        const int cs = (kc * 16 + lg * 4) ^ (((2 * dt + (lr >> 3)) & 7) << 2);
        bf16x8 vf = *(const bf16x8*)&Vs[row_d * 72 + cs * 2];
        o[0][dt] = MFMA16(vf, pf[0][kc], o[0][dt]);
        o[1][dt] = MFMA16(vf, pf[1][kc], o[1][dt]);
      }
    }
    __builtin_amdgcn_s_setprio(0);

    __syncthreads();                   // all waves done reading Ks/Vs
    if (kt < 63) STAGE_WRITE();        // T14: write-late (vmcnt drained here)
    __syncthreads();                   // next tile ready
  }

  // ---- epilogue: o holds ctx^T -> pack 4 consecutive d per b64 store ----
#pragma unroll
  for (int m = 0; m < 2; ++m) {
    float inv = 1.0f / ls[m];
#pragma unroll
    for (int dt = 0; dt < 4; ++dt) {
      u16x4 pk;
      pk[0] = f2bf(o[m][dt][0] * inv); pk[1] = f2bf(o[m][dt][1] * inv);
      pk[2] = f2bf(o[m][dt][2] * inv); pk[3] = f2bf(o[m][dt][3] * inv);
      *(u16x4*)&Og[(long)(q0 + m * 16 + lr) * 1024 + hb + dt * 16 + lg * 4] = pk;
    }
  }
#undef STAGE_LOAD
#undef STAGE_WRITE
}

extern "C" void kernel_launch(void* const* d_in, const int* in_sizes, int n_in,
                              void* d_out, int out_size, void* d_ws, size_t ws_size,
                              hipStream_t stream) {
  const float* x  = (const float*)d_in[0];
  const float* Wq = (const float*)d_in[1];
  const float* Wk = (const float*)d_in[2];
  const float* Wv = (const float*)d_in[3];
  const float* Wo = (const float*)d_in[4];
  const float* bo = (const float*)d_in[5];
  float* out = (float*)d_out;

  u16* xb  = (u16*)d_ws;            // 4096x1024 bf16
  u16* wb  = xb + 4194304;          // 4 x 1024x1024 bf16 (Wq,Wk,Wv,Wo)
  u16* qkv = wb + 4194304;          // Q,K,V each 4096x1024 bf16
  u16* ctx = qkv + 3 * 4194304;     // 4096x1024 bf16

  cvt_all<<<dim3(4096), dim3(256), 0, stream>>>(x, Wq, Wk, Wv, Wo, xb, wb);
  gemm_bt<0><<<dim3(32, 24), dim3(256), 0, stream>>>(xb, wb, qkv, nullptr, nullptr);
  attn<<<dim3(32, 16), dim3(256), 0, stream>>>(qkv, qkv + 4194304, qkv + 8388608, ctx);
  gemm_bt<1><<<dim3(32, 8), dim3(256), 0, stream>>>(ctx, wb + 3 * 1048576, nullptr, out, bo);
}

// Round 3
// 207.271 us; speedup vs baseline: 1.6838x; 1.0058x over previous
//
#include <hip/hip_runtime.h>

typedef short bf16x8 __attribute__((ext_vector_type(8)));
typedef float f32x4 __attribute__((ext_vector_type(4)));
typedef unsigned short u16;
typedef unsigned short u16x8 __attribute__((ext_vector_type(8)));

#define MFMA16(a, b, c) __builtin_amdgcn_mfma_f32_16x16x32_bf16((a), (b), (c), 0, 0, 0)

__device__ __forceinline__ u16 f2bf(float f) {
  unsigned u = __builtin_bit_cast(unsigned, f);
  return (u16)((u + 0x7fffu + ((u >> 16) & 1u)) >> 16);
}

__device__ __forceinline__ unsigned cvt_pk_bf16(float lo, float hi) {
  unsigned r;
  asm("v_cvt_pk_bf16_f32 %0, %1, %2" : "=v"(r) : "v"(lo), "v"(hi));
  return r;
}

__device__ __forceinline__ void gload_lds16(const u16* g, u16* lds) {
  __builtin_amdgcn_global_load_lds((__attribute__((address_space(1))) void*)g,
                                   (__attribute__((address_space(3))) void*)lds,
                                   16, 0, 0);
}

// ---------------- fp32 -> bf16 conversion (x + 4 weight mats) ----------------
__global__ __launch_bounds__(256) void cvt_all(
    const float* __restrict__ x, const float* __restrict__ w0,
    const float* __restrict__ w1, const float* __restrict__ w2,
    const float* __restrict__ w3, u16* __restrict__ xb, u16* __restrict__ wb) {
  long i = (long)(blockIdx.x * 256 + threadIdx.x) * 8;
  const float* src; u16* dst; long off;
  if (i < 4194304) { src = x; dst = xb; off = i; }
  else {
    long k = i - 4194304; int w = (int)(k >> 20); off = k & 1048575;
    src = (w == 0) ? w0 : (w == 1) ? w1 : (w == 2) ? w2 : w3;
    dst = wb + (long)w * 1048576;
  }
  float4 a = *(const float4*)(src + off);
  float4 b = *(const float4*)(src + off + 4);
  u16x8 o;
  o[0] = f2bf(a.x); o[1] = f2bf(a.y); o[2] = f2bf(a.z); o[3] = f2bf(a.w);
  o[4] = f2bf(b.x); o[5] = f2bf(b.y); o[6] = f2bf(b.z); o[7] = f2bf(b.w);
  *(u16x8*)(dst + off) = o;
}

// ---------------- GEMM  C[M,N] = A[M,K] * B[N,K]^T  (bf16 in, fp32 acc) -----
template <int MODE>
__global__ __launch_bounds__(256) void gemm_bt(
    const u16* __restrict__ A, const u16* __restrict__ Bw,
    u16* __restrict__ Co, float* __restrict__ Cf, const float* __restrict__ bias) {
  constexpr int K = 1024;
  __shared__ u16 As[128 * 32];
  __shared__ u16 Bs[128 * 32];
  const int tid = threadIdx.x, w = tid >> 6, l = tid & 63;
  const int lg = l >> 4, lr = l & 15;
  const int mb = blockIdx.x;
  int mat, nb;
  if (MODE == 0) { mat = blockIdx.y >> 3; nb = blockIdx.y & 7; }
  else           { mat = 0;               nb = blockIdx.y;     }
  const u16* __restrict__ Bp = Bw + (long)mat * 1048576;
  const int wr = w >> 1, wc = w & 1;
  f32x4 acc[4][4] = {};
  const int srow = (l >> 2), scol = (l & 3) * 8;
  for (int kt = 0; kt < K / 32; ++kt) {
    const int kb = kt * 32;
    __syncthreads();
#pragma unroll
    for (int i = 0; i < 2; ++i) {
      int r = w * 32 + i * 16 + srow;
      gload_lds16(A  + (long)(mb * 128 + r) * K + kb + scol, &As[(w * 2 + i) * 512]);
      gload_lds16(Bp + (long)(nb * 128 + r) * K + kb + scol, &Bs[(w * 2 + i) * 512]);
    }
    __syncthreads();
    bf16x8 af[4], bf[4];
#pragma unroll
    for (int m = 0; m < 4; ++m) af[m] = *(const bf16x8*)&As[(wr * 64 + m * 16 + lr) * 32 + lg * 8];
#pragma unroll
    for (int n = 0; n < 4; ++n) bf[n] = *(const bf16x8*)&Bs[(wc * 64 + n * 16 + lr) * 32 + lg * 8];
#pragma unroll
    for (int m = 0; m < 4; ++m)
#pragma unroll
      for (int n = 0; n < 4; ++n)
        acc[m][n] = MFMA16(af[m], bf[n], acc[m][n]);
  }
  const int row0 = mb * 128 + wr * 64, col0 = nb * 128 + wc * 64;
#pragma unroll
  for (int m = 0; m < 4; ++m)
#pragma unroll
    for (int n = 0; n < 4; ++n)
#pragma unroll
      for (int rr = 0; rr < 4; ++rr) {
        int row = row0 + m * 16 + lg * 4 + rr;
        int col = col0 + n * 16 + lr;
        float v = acc[m][n][rr];
        if (MODE == 0) {
          if (mat == 0) v *= 0.18033688011112042f;  // 0.125 * log2(e): softmax in exp2 domain
          Co[(long)mat * 4194304 + (long)row * 1024 + col] = f2bf(v);
        } else {
          Cf[(long)row * 1024 + col] = v + bias[col];
        }
      }
}

// ---------------- flash attention, swapped-QK^T, K-from-global, V dbuf ------
// S^T = mfma(K, Q): lane holds S[k][q=m*16+lr] -> softmax in-lane + 2 shfl.
// K frags read DIRECTLY from global (L1-broadcast across waves; L2-resident
// via XCD head-clustering swizzle), prefetched one iter ahead in regs.
// V staged transposed+swizzled in double-buffered LDS -> ONE barrier/iter.
// P roundtrip via wave-private LDS (same-wave DS is in-order, no barrier).
__global__ __launch_bounds__(256) void attn(
    const u16* __restrict__ Qg, const u16* __restrict__ Kg,
    const u16* __restrict__ Vg, u16* __restrict__ Og) {
  __shared__ u16 Vsb[2 * 64 * 72];  // V^T dbuf [d][k], pitch 72, dword-swizzled
  __shared__ u16 Ps[4 * 32 * 72];   // per-wave P [q 32][k 64], pitch 72
  const int tid = threadIdx.x, w = tid >> 6, l = tid & 63;
  const int lg = l >> 4, lr = l & 15;

  // XCD clustering: lin%8 = XCD (dispatch round-robin heuristic); 2 heads/XCD
  // -> K+V working set 2 MB < 4 MB L2 per XCD.
  const int lin = blockIdx.x;
  const int xcd = lin & 7, idx = lin >> 3;
  const int head = xcd * 2 + (idx >> 5), qt = idx & 31;
  const int hb = head * 64;
  const int q0 = qt * 128 + w * 32;

  const u16* __restrict__ Kh = Kg + hb;
  u16* Vs0 = Vsb;
  u16* Vs1 = Vsb + 64 * 72;
  u16* Pw = &Ps[w * 32 * 72];

  // Q fragments (B-operand of QK^T): Q[q = m*16+lr][d = dc*32+lg*8]
  bf16x8 qf[2][2];
#pragma unroll
  for (int m = 0; m < 2; ++m)
#pragma unroll
    for (int dc = 0; dc < 2; ++dc)
      qf[m][dc] = *(const bf16x8*)&Qg[(long)(q0 + m * 16 + lr) * 1024 + hb + dc * 32 + lg * 8];

  f32x4 o[2][4] = {};
  float mr[2] = {-1e30f, -1e30f}, ls[2] = {0.f, 0.f};

  // V staging geometry: 256 threads cover row pairs (2*kr, 2*kr+1), octet c8.
  const int kr = tid >> 3, c8 = tid & 7;
  const u16* Vgp = Vg + hb + c8 * 8;
  bf16x8 vst0, vst1;
  bf16x8 kA[4][2], kB[4][2];

#define KLOAD(dst, t_)                                                        \
  {                                                                           \
    long kb_ = (long)(t_) * 64;                                               \
    _Pragma("unroll") for (int nt = 0; nt < 4; ++nt)                          \
      _Pragma("unroll") for (int dc = 0; dc < 2; ++dc)                        \
        (dst)[nt][dc] =                                                       \
            *(const bf16x8*)&Kh[(kb_ + nt * 16 + lr) * 1024 + dc * 32 + lg * 8]; \
  }

#define VLOAD(t_)                                                \
  {                                                              \
    long kb_ = (long)(t_) * 64;                                  \
    vst0 = *(const bf16x8*)&Vgp[(kb_ + kr * 2) * 1024];          \
    vst1 = *(const bf16x8*)&Vgp[(kb_ + kr * 2 + 1) * 1024];      \
  }

#define VWRITE(dstV)                                                          \
  {                                                                           \
    const int cw = (kr ^ (c8 << 2)) * 2;                                      \
    _Pragma("unroll") for (int j = 0; j < 8; ++j) {                           \
      unsigned pk = (unsigned)(u16)vst0[j] | ((unsigned)(u16)vst1[j] << 16);  \
      *(unsigned*)&(dstV)[(c8 * 8 + j) * 72 + cw] = pk;                       \
    }                                                                         \
  }

#define BODY(kcur, knxt, t_, Vcur, Vnxt, last_)                               \
  {                                                                           \
    if (!(last_)) VLOAD((t_) + 1); /* T14: issue loads under compute */       \
    f32x4 S[2][4] = {};                                                       \
    __builtin_amdgcn_s_setprio(1);                                            \
    _Pragma("unroll") for (int nt = 0; nt < 4; ++nt)                          \
      _Pragma("unroll") for (int dc = 0; dc < 2; ++dc) {                      \
        S[0][nt] = MFMA16((kcur)[nt][dc], qf[0][dc], S[0][nt]);               \
        S[1][nt] = MFMA16((kcur)[nt][dc], qf[1][dc], S[1][nt]);               \
      }                                                                       \
    __builtin_amdgcn_s_setprio(0);                                            \
    if (!(last_)) KLOAD(knxt, (t_) + 1); /* K prefetch for next iter */       \
    _Pragma("unroll") for (int m = 0; m < 2; ++m) {                           \
      float t0 = fmaxf(fmaxf(S[m][0][0], S[m][0][1]), fmaxf(S[m][0][2], S[m][0][3])); \
      float t1 = fmaxf(fmaxf(S[m][1][0], S[m][1][1]), fmaxf(S[m][1][2], S[m][1][3])); \
      float t2 = fmaxf(fmaxf(S[m][2][0], S[m][2][1]), fmaxf(S[m][2][2], S[m][2][3])); \
      float t3 = fmaxf(fmaxf(S[m][3][0], S[m][3][1]), fmaxf(S[m][3][2], S[m][3][3])); \
      float mx = fmaxf(fmaxf(t0, t1), fmaxf(t2, t3));                         \
      mx = fmaxf(mx, __shfl_xor(mx, 16));                                     \
      mx = fmaxf(mx, __shfl_xor(mx, 32));                                     \
      if (!__all(mx <= mr[m] + 8.f)) { /* T13 defer-max, THR=8 (exp2 dom) */  \
        float mn = fmaxf(mr[m], mx);                                          \
        float al = __builtin_amdgcn_exp2f(mr[m] - mn);                        \
        mr[m] = mn;                                                           \
        ls[m] *= al;                                                          \
        _Pragma("unroll") for (int dt = 0; dt < 4; ++dt)                      \
          _Pragma("unroll") for (int rr = 0; rr < 4; ++rr) o[m][dt][rr] *= al;\
      }                                                                       \
      float sm = 0.f;                                                         \
      _Pragma("unroll") for (int nt = 0; nt < 4; ++nt)                        \
        _Pragma("unroll") for (int rr = 0; rr < 4; ++rr) {                    \
          S[m][nt][rr] = __builtin_amdgcn_exp2f(S[m][nt][rr] - mr[m]);        \
          sm += S[m][nt][rr];                                                 \
        }                                                                     \
      sm += __shfl_xor(sm, 16);                                               \
      sm += __shfl_xor(sm, 32);                                               \
      ls[m] += sm;                                                            \
      _Pragma("unroll") for (int nt = 0; nt < 4; ++nt) {                      \
        uint2 pk;                                                             \
        pk.x = cvt_pk_bf16(S[m][nt][0], S[m][nt][1]);                         \
        pk.y = cvt_pk_bf16(S[m][nt][2], S[m][nt][3]);                         \
        *(uint2*)&Pw[(m * 16 + lr) * 72 + nt * 16 + lg * 4] = pk;             \
      }                                                                       \
    }                                                                         \
    bf16x8 pf[2][2];                                                          \
    _Pragma("unroll") for (int m = 0; m < 2; ++m)                             \
      _Pragma("unroll") for (int kc = 0; kc < 2; ++kc)                        \
        pf[m][kc] = *(const bf16x8*)&Pw[(m * 16 + lr) * 72 + kc * 32 + lg * 8]; \
    __builtin_amdgcn_s_setprio(1);                                            \
    _Pragma("unroll") for (int dt = 0; dt < 4; ++dt) {                        \
      const int row_d = dt * 16 + lr;                                         \
      _Pragma("unroll") for (int kc = 0; kc < 2; ++kc) {                      \
        const int cs = (kc * 16 + lg * 4) ^ (((2 * dt + (lr >> 3)) & 7) << 2);\
        bf16x8 vf = *(const bf16x8*)&(Vcur)[row_d * 72 + cs * 2];             \
        o[0][dt] = MFMA16(vf, pf[0][kc], o[0][dt]);                           \
        o[1][dt] = MFMA16(vf, pf[1][kc], o[1][dt]);                           \
      }                                                                       \
    }                                                                         \
    __builtin_amdgcn_s_setprio(0);                                            \
    if (!(last_)) VWRITE(Vnxt); /* T14 write-late: vmcnt drained here */      \
    __syncthreads();            /* single barrier per iter (V dbuf) */        \
  }

  // prologue
  KLOAD(kA, 0);
  VLOAD(0);
  VWRITE(Vs0);
  __syncthreads();

  for (int t2 = 0; t2 < 32; ++t2) {
    const int t = t2 * 2;
    BODY(kA, kB, t, Vs0, Vs1, false);
    BODY(kB, kA, t + 1, Vs1, Vs0, t2 == 31);
  }

  // epilogue: o holds ctx^T -> pack 4 consecutive d per b64 store
#pragma unroll
  for (int m = 0; m < 2; ++m) {
    float inv = 1.0f / ls[m];
#pragma unroll
    for (int dt = 0; dt < 4; ++dt) {
      uint2 pk;
      pk.x = cvt_pk_bf16(o[m][dt][0] * inv, o[m][dt][1] * inv);
      pk.y = cvt_pk_bf16(o[m][dt][2] * inv, o[m][dt][3] * inv);
      *(uint2*)&Og[(long)(q0 + m * 16 + lr) * 1024 + hb + dt * 16 + lg * 4] = pk;
    }
  }
#undef KLOAD
#undef VLOAD
#undef VWRITE
#undef BODY
}

extern "C" void kernel_launch(void* const* d_in, const int* in_sizes, int n_in,
                              void* d_out, int out_size, void* d_ws, size_t ws_size,
                              hipStream_t stream) {
  const float* x  = (const float*)d_in[0];
  const float* Wq = (const float*)d_in[1];
  const float* Wk = (const float*)d_in[2];
  const float* Wv = (const float*)d_in[3];
  const float* Wo = (const float*)d_in[4];
  const float* bo = (const float*)d_in[5];
  float* out = (float*)d_out;

  u16* xb  = (u16*)d_ws;            // 4096x1024 bf16
  u16* wb  = xb + 4194304;          // 4 x 1024x1024 bf16 (Wq,Wk,Wv,Wo)
  u16* qkv = wb + 4194304;          // Q,K,V each 4096x1024 bf16
  u16* ctx = qkv + 3 * 4194304;     // 4096x1024 bf16

  cvt_all<<<dim3(4096), dim3(256), 0, stream>>>(x, Wq, Wk, Wv, Wo, xb, wb);
  gemm_bt<0><<<dim3(32, 24), dim3(256), 0, stream>>>(xb, wb, qkv, nullptr, nullptr);
  attn<<<dim3(512), dim3(256), 0, stream>>>(qkv, qkv + 4194304, qkv + 8388608, ctx);
  gemm_bt<1><<<dim3(32, 8), dim3(256), 0, stream>>>(ctx, wb + 3 * 1048576, nullptr, out, bo);
}